// Round 7
// baseline (172.035 us; speedup 1.0000x reference)
//
#include <hip/hip_runtime.h>
#include <hip/hip_bf16.h>
#include <math.h>

#define NN 4096
#define IN_DIM 256
#define OUT_DIM 128
#define HEADS 4
#define SUB 32
#define MAXDEG 128
#define ETA 0.5f
#define INV_SQRT_SUB 0.17677669529663687f

typedef __attribute__((ext_vector_type(8))) short bf16x8;
typedef __attribute__((ext_vector_type(4))) short s16x4;
typedef __attribute__((ext_vector_type(4))) float f32x4;

static __device__ inline short f2bf(float f) {
    unsigned u = __float_as_uint(f);
    unsigned r = u + 0x7FFFu + ((u >> 16) & 1u);
    return (short)(r >> 16);
}
static __device__ inline float bf2f(short s) {
    return __uint_as_float(((unsigned)(unsigned short)s) << 16);
}
#define MFMA16(a, b, c) __builtin_amdgcn_mfma_f32_16x16x32_bf16(a, b, c, 0, 0, 0)

// ---- K0: prep Wh/Wl (split-bf16 of [U cols | PW rows]) | W2T | orth loss partials ----
__global__ __launch_bounds__(256) void fused_small(const float* __restrict__ U,
                                                   const float* __restrict__ PW,
                                                   short* __restrict__ Wh,
                                                   short* __restrict__ Wl,
                                                   float* __restrict__ W2T,
                                                   float* __restrict__ loss_parts) {
    int b = blockIdx.x;
    int t = threadIdx.x;
    __shared__ float sh[260];

    if (b < 256) {
        float v;
        if (b < 128) {
            int h = b >> 5, s = b & 31;
            v = U[h * IN_DIM * SUB + t * SUB + s];
        } else {
            v = PW[(b - 128) * IN_DIM + t];
        }
        short hi = f2bf(v);
        Wh[b * IN_DIM + t] = hi;
        Wl[b * IN_DIM + t] = f2bf(v - bf2f(hi));
    } else if (b < 384) {
        int hs = b - 256;
        int h = hs >> 5, s = hs & 31;
        sh[t] = U[h * IN_DIM * SUB + t * SUB + s];
        __syncthreads();
        if (t < 128) {
            const float4* pw4 = (const float4*)(PW + t * IN_DIM);
            const float4* u4  = (const float4*)sh;
            float acc = 0.f;
            #pragma unroll 4
            for (int d4 = 0; d4 < 64; ++d4) {
                float4 a = u4[d4], p = pw4[d4];
                acc += a.x * p.x + a.y * p.y + a.z * p.z + a.w * p.w;
            }
            W2T[t * OUT_DIM + hs] = acc;      // [o][hs]
        }
    } else {
        const int pk[10] = {0,0,0,0,1,1,1,2,2,3};
        const int pl[10] = {0,1,2,3,1,2,3,2,3,3};
        int p = b - 384;
        int k = pk[p], l = pl[p];
        int t2 = t & 31;
        int sg = t >> 5;
        const float* Uk = U + k * IN_DIM * SUB;
        const float* Ul = U + l * IN_DIM * SUB;
        float a0 = 0.f, a1 = 0.f, a2 = 0.f, a3 = 0.f;
        #pragma unroll 4
        for (int d = 0; d < IN_DIM; ++d) {
            float ul = Ul[d * SUB + t2];
            float u0 = Uk[d * SUB + sg * 4 + 0];
            float u1 = Uk[d * SUB + sg * 4 + 1];
            float u2 = Uk[d * SUB + sg * 4 + 2];
            float u3 = Uk[d * SUB + sg * 4 + 3];
            a0 += u0 * ul; a1 += u1 * ul; a2 += u2 * ul; a3 += u3 * ul;
        }
        if (k == l) {
            if (sg * 4 + 0 == t2) a0 -= 1.f;
            if (sg * 4 + 1 == t2) a1 -= 1.f;
            if (sg * 4 + 2 == t2) a2 -= 1.f;
            if (sg * 4 + 3 == t2) a3 -= 1.f;
        }
        float local = a0 * a0 + a1 * a1 + a2 * a2 + a3 * a3;
        local += __shfl_xor(local, 32, 64);
        local += __shfl_xor(local, 16, 64);
        local += __shfl_xor(local, 8, 64);
        local += __shfl_xor(local, 4, 64);
        local += __shfl_xor(local, 2, 64);
        local += __shfl_xor(local, 1, 64);
        if ((t & 63) == 0) sh[256 + (t >> 6)] = local;
        __syncthreads();
        if (t == 0) loss_parts[p] = sh[256] + sh[257] + sh[258] + sh[259];
    }
}

// ---- K1: [ZT | P] = H @ W^T via split-bf16 MFMA (3-term, fp32-accurate) ----
#define LDA 264
__global__ __launch_bounds__(256) void ztp_mfma(const float* __restrict__ H,
                                                const short* __restrict__ Wh,
                                                const short* __restrict__ Wl,
                                                float* __restrict__ ZT,
                                                float* __restrict__ P) {
    __shared__ short Ah[16 * LDA];
    __shared__ short Al[16 * LDA];
    int t = threadIdx.x, b = blockIdx.x;
    int m0 = (b >> 1) * 16, chalf = b & 1;

    {
        int r = t >> 4, dbase = (t & 15) * 16;
        const float4* src = (const float4*)(H + (size_t)(m0 + r) * IN_DIM + dbase);
        #pragma unroll
        for (int q = 0; q < 4; ++q) {
            float4 f = src[q];
            float fv[4] = {f.x, f.y, f.z, f.w};
            s16x4 hi, lo;
            #pragma unroll
            for (int j = 0; j < 4; ++j) {
                short h = f2bf(fv[j]);
                hi[j] = h;
                lo[j] = f2bf(fv[j] - bf2f(h));
            }
            *(s16x4*)&Ah[r * LDA + dbase + q * 4] = hi;
            *(s16x4*)&Al[r * LDA + dbase + q * 4] = lo;
        }
    }
    __syncthreads();

    int wave = t >> 6, lane = t & 63;
    int c0 = chalf * 128 + wave * 32;
    int arow = lane & 15, agrp = lane >> 4;

    const short* ahp = &Ah[arow * LDA + agrp * 8];
    const short* alp = &Al[arow * LDA + agrp * 8];
    const short* bh0 = Wh + (size_t)(c0 + arow) * IN_DIM + agrp * 8;
    const short* bl0 = Wl + (size_t)(c0 + arow) * IN_DIM + agrp * 8;
    const short* bh1 = bh0 + 16 * IN_DIM;
    const short* bl1 = bl0 + 16 * IN_DIM;

    f32x4 acc0 = {0.f, 0.f, 0.f, 0.f};
    f32x4 acc1 = {0.f, 0.f, 0.f, 0.f};

    #pragma unroll
    for (int kk = 0; kk < 8; ++kk) {
        int d0 = kk * 32;
        bf16x8 a_h = *(const bf16x8*)(ahp + d0);
        bf16x8 a_l = *(const bf16x8*)(alp + d0);
        bf16x8 b0h = *(const bf16x8*)(bh0 + d0);
        bf16x8 b0l = *(const bf16x8*)(bl0 + d0);
        bf16x8 b1h = *(const bf16x8*)(bh1 + d0);
        bf16x8 b1l = *(const bf16x8*)(bl1 + d0);
        acc0 = MFMA16(a_h, b0h, acc0);
        acc0 = MFMA16(a_h, b0l, acc0);
        acc0 = MFMA16(a_l, b0h, acc0);
        acc1 = MFMA16(a_h, b1h, acc1);
        acc1 = MFMA16(a_h, b1l, acc1);
        acc1 = MFMA16(a_l, b1h, acc1);
    }

    float* dst = chalf ? P : ZT;
    int colbase = c0 - chalf * 128;
    #pragma unroll
    for (int i = 0; i < 4; ++i) {
        int row = m0 + agrp * 4 + i;
        dst[(size_t)row * 128 + colbase + arow]      = acc0[i];
        dst[(size_t)row * 128 + colbase + 16 + arow] = acc1[i];
    }
}

// ---- K2: scan + shuffle-free attention + fused epilogue, 2 rows/block ----
__global__ __launch_bounds__(256) void attn_fused(const float* __restrict__ ZT,
                                                  const float* __restrict__ Pm,
                                                  const float* __restrict__ W2T,
                                                  const float* __restrict__ adj,
                                                  const float* __restrict__ threshold,
                                                  const float* __restrict__ loss_parts,
                                                  float* __restrict__ out) {
    int b = blockIdx.x, t = threadIdx.x;
    int half = t >> 7, u = t & 127;
    int row = b * 2 + half;
    __shared__ int   nbr_s[2][MAXDEG];
    __shared__ float e_s[2][MAXDEG][HEADS];
    __shared__ float z_s[2][128];
    __shared__ float agg_s[2][128];
    __shared__ int cnt[2];

    if (b == 0 && t == 0) {
        float L = 0.f;
        #pragma unroll
        for (int p = 0; p < 10; ++p) L += loss_parts[p];
        out[(size_t)NN * OUT_DIM] = L;
    }

    // prefetch the whole adjacency row slice (8 float4 = 32 VGPRs in flight)
    const float4* row4 = (const float4*)(adj + (size_t)row * NN);
    float4 v[8];
    #pragma unroll
    for (int k = 0; k < 8; ++k) v[k] = row4[u + k * 128];

    if (u == 0) cnt[half] = 0;
    nbr_s[half][u] = 0;
    z_s[half][u] = ZT[(size_t)row * 128 + u];
    __syncthreads();

    #pragma unroll
    for (int k = 0; k < 8; ++k) {
        int j0 = (u + k * 128) * 4;
        if (v[k].x > 0.5f) { int p = atomicAdd(&cnt[half], 1); if (p < MAXDEG) nbr_s[half][p] = j0; }
        if (v[k].y > 0.5f) { int p = atomicAdd(&cnt[half], 1); if (p < MAXDEG) nbr_s[half][p] = j0 + 1; }
        if (v[k].z > 0.5f) { int p = atomicAdd(&cnt[half], 1); if (p < MAXDEG) nbr_s[half][p] = j0 + 2; }
        if (v[k].w > 0.5f) { int p = atomicAdd(&cnt[half], 1); if (p < MAXDEG) nbr_s[half][p] = j0 + 3; }
    }
    __syncthreads();
    int dg = cnt[half] < MAXDEG ? cnt[half] : MAXDEG;

    // phase B: lane=(neighbor jj0=u>>2, head h=u&3); full 32-dot, no shuffles
    int jj0 = u >> 2, h = u & 3;
    int ntiles = (dg + 31) >> 5;
    const float4* qr = (const float4*)(&z_s[half][h * 32]);
    for (int tile = 0; tile < ntiles; ++tile) {
        int jj = tile * 32 + jj0;
        int j = nbr_s[half][jj];
        const float4* zr = (const float4*)(ZT + (size_t)j * 128 + h * 32);
        float acc = 0.f;
        #pragma unroll
        for (int k = 0; k < 8; ++k) {
            float4 z = zr[k];
            float4 q = qr[k];
            acc += z.x * q.x + z.y * q.y + z.z * q.z + z.w * q.w;
        }
        e_s[half][jj][h] = (jj < dg) ? __expf(acc * INV_SQRT_SUB) : 0.f;
    }
    __syncthreads();

    // phase C: weighted aggregation, coalesced ZT row slices
    int hh = u >> 5;
    float accV = 0.f, accS = 0.f;
    const float* zbase = ZT + u;
    for (int jj = 0; jj < dg; jj += 4) {
        int ja = nbr_s[half][jj],     jb = nbr_s[half][jj + 1];
        int jc = nbr_s[half][jj + 2], jd = nbr_s[half][jj + 3];
        float ea = e_s[half][jj][hh],     eb = e_s[half][jj + 1][hh];
        float ec = e_s[half][jj + 2][hh], ed = e_s[half][jj + 3][hh];
        float va = zbase[(size_t)ja * 128], vb = zbase[(size_t)jb * 128];
        float vc = zbase[(size_t)jc * 128], vd = zbase[(size_t)jd * 128];
        accV += ea * va + eb * vb + ec * vc + ed * vd;
        accS += (ea + eb) + (ec + ed);
    }
    agg_s[half][u] = accV * (ETA / accS);
    __syncthreads();

    // epilogue: out[row][u] = soft_thresh(P[row][u] + <agg, W2T[u]>)
    float val = Pm[(size_t)row * 128 + u];
    const float4* w4 = (const float4*)(W2T + u * 128);
    const float4* a4 = (const float4*)(&agg_s[half][0]);
    #pragma unroll 8
    for (int k = 0; k < 32; ++k) {
        float4 w = w4[k], a = a4[k];
        val += w.x * a.x + w.y * a.y + w.z * a.z + w.w * a.w;
    }
    float th = threshold[u];
    float av = fabsf(val) - th;
    out[(size_t)row * 128 + u] = (av > 0.f) ? copysignf(av, val) : 0.f;
}

extern "C" void kernel_launch(void* const* d_in, const int* in_sizes, int n_in,
                              void* d_out, int out_size, void* d_ws, size_t ws_size,
                              hipStream_t stream) {
    const float* H   = (const float*)d_in[0];
    const float* adj = (const float*)d_in[1];
    const float* U   = (const float*)d_in[2];
    const float* thr = (const float*)d_in[3];
    const float* PW  = (const float*)d_in[4];
    float* out = (float*)d_out;

    char* ws = (char*)d_ws;
    float* ZT    = (float*)(ws);                       // 2 MB
    float* P     = (float*)(ws + (size_t)2097152);     // 2 MB
    float* W2T   = (float*)(ws + (size_t)4194304);     // 64 KB
    short* Wh    = (short*)(ws + (size_t)4259840);     // 128 KB
    short* Wl    = (short*)(ws + (size_t)4390912);     // 128 KB
    float* lossp = (float*)(ws + (size_t)4521984);     // 40 B

    fused_small<<<394, 256, 0, stream>>>(U, PW, Wh, Wl, W2T, lossp);
    ztp_mfma<<<NN / 16 * 2, 256, 0, stream>>>(H, Wh, Wl, ZT, P);
    attn_fused<<<NN / 2, 256, 0, stream>>>(ZT, P, W2T, adj, thr, lossp, out);
}

// Round 8
// 149.024 us; speedup vs baseline: 1.1544x; 1.1544x over previous
//
#include <hip/hip_runtime.h>
#include <hip/hip_bf16.h>
#include <math.h>

#define NN 4096
#define IN_DIM 256
#define OUT_DIM 128
#define HEADS 4
#define SUB 32
#define MAXDEG 128
#define ETA 0.5f
#define INV_SQRT_SUB 0.17677669529663687f

typedef __attribute__((ext_vector_type(8))) short bf16x8;
typedef __attribute__((ext_vector_type(4))) short s16x4;
typedef __attribute__((ext_vector_type(4))) float f32x4;

static __device__ inline short f2bf(float f) {
    unsigned u = __float_as_uint(f);
    unsigned r = u + 0x7FFFu + ((u >> 16) & 1u);
    return (short)(r >> 16);
}
static __device__ inline float bf2f(short s) {
    return __uint_as_float(((unsigned)(unsigned short)s) << 16);
}
#define MFMA16(a, b, c) __builtin_amdgcn_mfma_f32_16x16x32_bf16(a, b, c, 0, 0, 0)

// ---- K0: prep Wh/Wl (split-bf16 of [U cols | PW rows]) | W2 | orth loss partials ----
__global__ __launch_bounds__(256) void fused_small(const float* __restrict__ U,
                                                   const float* __restrict__ PW,
                                                   short* __restrict__ Wh,
                                                   short* __restrict__ Wl,
                                                   float* __restrict__ W2,
                                                   float* __restrict__ loss_parts) {
    int b = blockIdx.x;
    int t = threadIdx.x;
    __shared__ float sh[260];

    if (b < 256) {
        float v;
        if (b < 128) {
            int h = b >> 5, s = b & 31;
            v = U[h * IN_DIM * SUB + t * SUB + s];
        } else {
            v = PW[(b - 128) * IN_DIM + t];
        }
        short hi = f2bf(v);
        Wh[b * IN_DIM + t] = hi;
        Wl[b * IN_DIM + t] = f2bf(v - bf2f(hi));
    } else if (b < 384) {
        int hs = b - 256;
        int h = hs >> 5, s = hs & 31;
        sh[t] = U[h * IN_DIM * SUB + t * SUB + s];
        __syncthreads();
        if (t < 128) {
            const float4* pw4 = (const float4*)(PW + t * IN_DIM);
            const float4* u4  = (const float4*)sh;
            float acc = 0.f;
            #pragma unroll 4
            for (int d4 = 0; d4 < 64; ++d4) {
                float4 a = u4[d4], p = pw4[d4];
                acc += a.x * p.x + a.y * p.y + a.z * p.z + a.w * p.w;
            }
            W2[hs * OUT_DIM + t] = acc;       // [hs][o] layout (coalesced per-o)
        }
    } else {
        const int pk[10] = {0,0,0,0,1,1,1,2,2,3};
        const int pl[10] = {0,1,2,3,1,2,3,2,3,3};
        int p = b - 384;
        int k = pk[p], l = pl[p];
        int t2 = t & 31;
        int sg = t >> 5;
        const float* Uk = U + k * IN_DIM * SUB;
        const float* Ul = U + l * IN_DIM * SUB;
        float a0 = 0.f, a1 = 0.f, a2 = 0.f, a3 = 0.f;
        #pragma unroll 4
        for (int d = 0; d < IN_DIM; ++d) {
            float ul = Ul[d * SUB + t2];
            float u0 = Uk[d * SUB + sg * 4 + 0];
            float u1 = Uk[d * SUB + sg * 4 + 1];
            float u2 = Uk[d * SUB + sg * 4 + 2];
            float u3 = Uk[d * SUB + sg * 4 + 3];
            a0 += u0 * ul; a1 += u1 * ul; a2 += u2 * ul; a3 += u3 * ul;
        }
        if (k == l) {
            if (sg * 4 + 0 == t2) a0 -= 1.f;
            if (sg * 4 + 1 == t2) a1 -= 1.f;
            if (sg * 4 + 2 == t2) a2 -= 1.f;
            if (sg * 4 + 3 == t2) a3 -= 1.f;
        }
        float local = a0 * a0 + a1 * a1 + a2 * a2 + a3 * a3;
        local += __shfl_xor(local, 32, 64);
        local += __shfl_xor(local, 16, 64);
        local += __shfl_xor(local, 8, 64);
        local += __shfl_xor(local, 4, 64);
        local += __shfl_xor(local, 2, 64);
        local += __shfl_xor(local, 1, 64);
        if ((t & 63) == 0) sh[256 + (t >> 6)] = local;
        __syncthreads();
        if (t == 0) loss_parts[p] = sh[256] + sh[257] + sh[258] + sh[259];
    }
}

// ---- K1: [ZT | P] = H @ W^T via split-bf16 MFMA (3-term, fp32-accurate) ----
#define LDA 264
__global__ __launch_bounds__(256) void ztp_mfma(const float* __restrict__ H,
                                                const short* __restrict__ Wh,
                                                const short* __restrict__ Wl,
                                                float* __restrict__ ZT,
                                                float* __restrict__ P) {
    __shared__ short Ah[16 * LDA];
    __shared__ short Al[16 * LDA];
    int t = threadIdx.x, b = blockIdx.x;
    int m0 = (b >> 1) * 16, chalf = b & 1;

    {
        int r = t >> 4, dbase = (t & 15) * 16;
        const float4* src = (const float4*)(H + (size_t)(m0 + r) * IN_DIM + dbase);
        #pragma unroll
        for (int q = 0; q < 4; ++q) {
            float4 f = src[q];
            float fv[4] = {f.x, f.y, f.z, f.w};
            s16x4 hi, lo;
            #pragma unroll
            for (int j = 0; j < 4; ++j) {
                short h = f2bf(fv[j]);
                hi[j] = h;
                lo[j] = f2bf(fv[j] - bf2f(h));
            }
            *(s16x4*)&Ah[r * LDA + dbase + q * 4] = hi;
            *(s16x4*)&Al[r * LDA + dbase + q * 4] = lo;
        }
    }
    __syncthreads();

    int wave = t >> 6, lane = t & 63;
    int c0 = chalf * 128 + wave * 32;
    int arow = lane & 15, agrp = lane >> 4;

    const short* ahp = &Ah[arow * LDA + agrp * 8];
    const short* alp = &Al[arow * LDA + agrp * 8];
    const short* bh0 = Wh + (size_t)(c0 + arow) * IN_DIM + agrp * 8;
    const short* bl0 = Wl + (size_t)(c0 + arow) * IN_DIM + agrp * 8;
    const short* bh1 = bh0 + 16 * IN_DIM;
    const short* bl1 = bl0 + 16 * IN_DIM;

    f32x4 acc0 = {0.f, 0.f, 0.f, 0.f};
    f32x4 acc1 = {0.f, 0.f, 0.f, 0.f};

    #pragma unroll
    for (int kk = 0; kk < 8; ++kk) {
        int d0 = kk * 32;
        bf16x8 a_h = *(const bf16x8*)(ahp + d0);
        bf16x8 a_l = *(const bf16x8*)(alp + d0);
        bf16x8 b0h = *(const bf16x8*)(bh0 + d0);
        bf16x8 b0l = *(const bf16x8*)(bl0 + d0);
        bf16x8 b1h = *(const bf16x8*)(bh1 + d0);
        bf16x8 b1l = *(const bf16x8*)(bl1 + d0);
        acc0 = MFMA16(a_h, b0h, acc0);
        acc0 = MFMA16(a_h, b0l, acc0);
        acc0 = MFMA16(a_l, b0h, acc0);
        acc1 = MFMA16(a_h, b1h, acc1);
        acc1 = MFMA16(a_h, b1l, acc1);
        acc1 = MFMA16(a_l, b1h, acc1);
    }

    float* dst = chalf ? P : ZT;
    int colbase = c0 - chalf * 128;
    #pragma unroll
    for (int i = 0; i < 4; ++i) {
        int row = m0 + agrp * 4 + i;
        dst[(size_t)row * 128 + colbase + arow]      = acc0[i];
        dst[(size_t)row * 128 + colbase + 16 + arow] = acc1[i];
    }
}

// ---- K2: scan + shuffle-free attention + fused epilogue, 1 row / 128 threads ----
__global__ __launch_bounds__(128) void attn_core(const float* __restrict__ ZT,
                                                 const float* __restrict__ Pm,
                                                 const float* __restrict__ W2,
                                                 const float* __restrict__ adj,
                                                 const float* __restrict__ threshold,
                                                 const float* __restrict__ loss_parts,
                                                 float* __restrict__ out) {
    int i = blockIdx.x;
    int t = threadIdx.x;
    __shared__ int   nbr_s[MAXDEG];
    __shared__ float e_s[MAXDEG][HEADS];
    __shared__ float z_s[128];
    __shared__ float agg_s[128];
    __shared__ int cnt;

    if (i == 0 && t == 0) {
        float L = 0.f;
        #pragma unroll
        for (int p = 0; p < 10; ++p) L += loss_parts[p];
        out[(size_t)NN * OUT_DIM] = L;
    }

    // prefetch the whole adjacency row slice (8 float4 = 32 VGPRs in flight)
    const float4* row4 = (const float4*)(adj + (size_t)i * NN);
    float4 v[8];
    #pragma unroll
    for (int k = 0; k < 8; ++k) v[k] = row4[t + k * 128];

    if (t == 0) cnt = 0;
    nbr_s[t] = 0;
    z_s[t] = ZT[(size_t)i * 128 + t];
    __syncthreads();

    #pragma unroll
    for (int k = 0; k < 8; ++k) {
        int j0 = (t + k * 128) * 4;
        if (v[k].x > 0.5f) { int p = atomicAdd(&cnt, 1); if (p < MAXDEG) nbr_s[p] = j0; }
        if (v[k].y > 0.5f) { int p = atomicAdd(&cnt, 1); if (p < MAXDEG) nbr_s[p] = j0 + 1; }
        if (v[k].z > 0.5f) { int p = atomicAdd(&cnt, 1); if (p < MAXDEG) nbr_s[p] = j0 + 2; }
        if (v[k].w > 0.5f) { int p = atomicAdd(&cnt, 1); if (p < MAXDEG) nbr_s[p] = j0 + 3; }
    }
    __syncthreads();
    int dg = cnt < MAXDEG ? cnt : MAXDEG;

    // phase B: lane=(neighbor jj0=t>>2, head h=t&3); full 32-dot, no shuffles
    int jj0 = t >> 2, h = t & 3;
    int ntiles = (dg + 31) >> 5;
    const float4* qr = (const float4*)(&z_s[h * 32]);
    for (int tile = 0; tile < ntiles; ++tile) {
        int jj = tile * 32 + jj0;
        int j = nbr_s[jj];
        const float4* zr = (const float4*)(ZT + (size_t)j * 128 + h * 32);
        float acc = 0.f;
        #pragma unroll
        for (int k = 0; k < 8; ++k) {
            float4 z = zr[k];
            float4 q = qr[k];
            acc += z.x * q.x + z.y * q.y + z.z * q.z + z.w * q.w;
        }
        e_s[jj][h] = (jj < dg) ? __expf(acc * INV_SQRT_SUB) : 0.f;
    }
    __syncthreads();

    // phase C: weighted aggregation, coalesced ZT row slices
    int hh = t >> 5;
    float accV = 0.f, accS = 0.f;
    const float* zbase = ZT + t;
    for (int jj = 0; jj < dg; jj += 4) {
        int ja = nbr_s[jj],     jb = nbr_s[jj + 1];
        int jc = nbr_s[jj + 2], jd = nbr_s[jj + 3];
        float ea = e_s[jj][hh],     eb = e_s[jj + 1][hh];
        float ec = e_s[jj + 2][hh], ed = e_s[jj + 3][hh];
        float va = zbase[(size_t)ja * 128], vb = zbase[(size_t)jb * 128];
        float vc = zbase[(size_t)jc * 128], vd = zbase[(size_t)jd * 128];
        accV += ea * va + eb * vb + ec * vc + ed * vd;
        accS += (ea + eb) + (ec + ed);
    }
    agg_s[t] = accV * (ETA / accS);
    __syncthreads();

    // fused epilogue: out[i][t] = soft_thresh(P[i][t] + sum_hs agg[hs]*W2[hs][t])
    float val = Pm[(size_t)i * 128 + t];
    #pragma unroll 4
    for (int q4 = 0; q4 < 32; ++q4) {
        int hs = q4 * 4;
        float w0 = W2[(hs + 0) * 128 + t];     // coalesced, L2-resident
        float w1 = W2[(hs + 1) * 128 + t];
        float w2v = W2[(hs + 2) * 128 + t];
        float w3 = W2[(hs + 3) * 128 + t];
        float4 a = *(const float4*)&agg_s[hs]; // LDS broadcast
        val += a.x * w0 + a.y * w1 + a.z * w2v + a.w * w3;
    }
    float th = threshold[t];
    float av = fabsf(val) - th;
    out[(size_t)i * 128 + t] = (av > 0.f) ? copysignf(av, val) : 0.f;
}

extern "C" void kernel_launch(void* const* d_in, const int* in_sizes, int n_in,
                              void* d_out, int out_size, void* d_ws, size_t ws_size,
                              hipStream_t stream) {
    const float* H   = (const float*)d_in[0];
    const float* adj = (const float*)d_in[1];
    const float* U   = (const float*)d_in[2];
    const float* thr = (const float*)d_in[3];
    const float* PW  = (const float*)d_in[4];
    float* out = (float*)d_out;

    char* ws = (char*)d_ws;
    float* ZT    = (float*)(ws);                       // 2 MB
    float* P     = (float*)(ws + (size_t)2097152);     // 2 MB
    float* W2    = (float*)(ws + (size_t)4194304);     // 64 KB
    short* Wh    = (short*)(ws + (size_t)4259840);     // 128 KB
    short* Wl    = (short*)(ws + (size_t)4390912);     // 128 KB
    float* lossp = (float*)(ws + (size_t)4521984);     // 40 B

    fused_small<<<394, 256, 0, stream>>>(U, PW, Wh, Wl, W2, lossp);
    ztp_mfma<<<NN / 16 * 2, 256, 0, stream>>>(H, Wh, Wl, ZT, P);
    attn_core<<<NN, 128, 0, stream>>>(ZT, P, W2, adj, thr, lossp, out);
}